// Round 5
// baseline (862.280 us; speedup 1.0000x reference)
//
#include <hip/hip_runtime.h>

#define NSRC 100000
#define NTGT 50000
#define NE   600000
#define CH   128
#define NREL 7
#define NTYP 4
#define NP   (NREL * NTGT)          // 350000 (rel,dst) pairs
#define NB   ((NP + 1023) / 1024)   // scan blocks (342)
#define TR   32                     // dst rows per tile
#define NTILE ((NTGT + TR - 1) / TR) // 1563

typedef __attribute__((ext_vector_type(4))) float f32x4;
typedef __attribute__((ext_vector_type(8))) short bf16x8;
typedef unsigned int uint;
typedef unsigned short ushort;

// ---- workspace layout ----
static constexpr size_t A256(size_t x) { return (x + 255) & ~(size_t)255; }
static constexpr size_t CNT_O   = 0;                                   // int[NP] (zeroed)
static constexpr size_t ZERO_END= A256(CNT_O + (size_t)NP * 4);
static constexpr size_t EOFF_O  = ZERO_END;                            // int[NP+1]
static constexpr size_t CUR_O   = A256(EOFF_O + (size_t)(NP + 64) * 4);// int[NP]
static constexpr size_t BSE_O   = A256(CUR_O + (size_t)NP * 4);        // int[NB]
static constexpr size_t BBE_O   = A256(BSE_O + (size_t)NB * 4);        // int[NB]
static constexpr size_t SEDGE_O = A256(BBE_O + (size_t)NB * 4);        // uint2[NE] 4.8MB
static constexpr size_t WB_O    = A256(SEDGE_O + (size_t)NE * 8);      // bf16[11*CH*CH]
static constexpr size_t XB_O    = A256(WB_O + (size_t)(NREL + NTYP) * CH * CH * 2); // bf16[NSRC*CH]
static constexpr size_t XTB_O   = A256(XB_O + (size_t)NSRC * CH * 2);  // bf16[NTGT*CH]

__device__ __forceinline__ uint bfpack(float a, float b) {
  uint ua = __float_as_uint(a); ua = (ua + 0x7fff + ((ua >> 16) & 1)) >> 16;
  uint ub = __float_as_uint(b); ub = (ub + 0x7fff + ((ub >> 16) & 1)) >> 16;
  return ua | (ub << 16);
}
__device__ __forceinline__ ushort f2b(float x) {
  uint u = __float_as_uint(x);
  return (ushort)((u + 0x7fff + ((u >> 16) & 1)) >> 16);
}
__device__ __forceinline__ float bl(uint u) { return __uint_as_float(u << 16); }
__device__ __forceinline__ float bh(uint u) { return __uint_as_float(u & 0xffff0000u); }

__global__ void k_count(const int* __restrict__ edst, const int* __restrict__ etyp,
                        int* __restrict__ cnt) {
  int i = blockIdx.x * 256 + threadIdx.x;
  if (i < NE) atomicAdd(&cnt[etyp[i] * NTGT + edst[i]], 1);
}

// scan stage 1: per-1024-entry block sums of edge counts
__global__ __launch_bounds__(256) void k_s1(const int* __restrict__ cnt,
                                            int* __restrict__ bsE) {
  __shared__ int sE[256];
  int t = threadIdx.x, p0 = blockIdx.x * 1024 + t * 4;
  int e = 0;
#pragma unroll
  for (int j = 0; j < 4; ++j) {
    int p = p0 + j;
    if (p < NP) e += cnt[p];
  }
  sE[t] = e; __syncthreads();
  for (int s = 128; s > 0; s >>= 1) {
    if (t < s) sE[t] += sE[t + s];
    __syncthreads();
  }
  if (t == 0) bsE[blockIdx.x] = sE[0];
}

// scan stage 2: exclusive scan of block sums; also seed eoff[NP]=NE
__global__ __launch_bounds__(512) void k_s2(const int* __restrict__ bsE,
                                            int* __restrict__ bbE, int* __restrict__ eoff) {
  __shared__ int sE[512];
  int t = threadIdx.x;
  int e = (t < NB) ? bsE[t] : 0;
  sE[t] = e; __syncthreads();
  for (int s = 1; s < 512; s <<= 1) {
    int ae = 0;
    if (t >= s) ae = sE[t - s];
    __syncthreads();
    sE[t] += ae;
    __syncthreads();
  }
  if (t < NB) bbE[t] = sE[t] - e;
  if (t == 0) eoff[NP] = NE;
}

// scan stage 3: final per-pair offsets -> eoff (stable) and cur (bump pointers)
__global__ __launch_bounds__(256) void k_s3(const int* __restrict__ cnt,
    const int* __restrict__ bbE, int* __restrict__ eoff, int* __restrict__ cur) {
  __shared__ int sE[256];
  int t = threadIdx.x, p0 = blockIdx.x * 1024 + t * 4;
  int c[4]; int e = 0;
#pragma unroll
  for (int j = 0; j < 4; ++j) {
    int p = p0 + j;
    c[j] = (p < NP) ? cnt[p] : 0;
    e += c[j];
  }
  sE[t] = e; __syncthreads();
  for (int s = 1; s < 256; s <<= 1) {
    int ae = 0;
    if (t >= s) ae = sE[t - s];
    __syncthreads();
    sE[t] += ae;
    __syncthreads();
  }
  int baseE = bbE[blockIdx.x] + sE[t] - e;
#pragma unroll
  for (int j = 0; j < 4; ++j) {
    int p = p0 + j;
    if (p < NP) {
      eoff[p] = baseE; cur[p] = baseE;
      baseE += c[j];
    }
  }
}

// place edges sorted by (rel, dst); store (src, dst) pairs
__global__ void k_esort(const int* __restrict__ esrc, const int* __restrict__ edst,
                        const int* __restrict__ etyp, int* __restrict__ cur,
                        uint2* __restrict__ sedge) {
  int i = blockIdx.x * 256 + threadIdx.x;
  if (i < NE) {
    int d = edst[i];
    int p = etyp[i] * NTGT + d;
    int pos = atomicAdd(&cur[p], 1);
    sedge[pos] = make_uint2((uint)esrc[i], (uint)d);
  }
}

// fp32 -> bf16 conversion for x_src, x_target, and all weights (one pass)
__global__ void k_conv(const float* __restrict__ xsrc, const float* __restrict__ xt,
                       const float* __restrict__ relw, const float* __restrict__ rootw,
                       ushort* __restrict__ xb, ushort* __restrict__ xtb,
                       ushort* __restrict__ wb) {
  const long long NXB = (long long)NSRC * CH / 4;
  const long long NXT = (long long)NTGT * CH / 4;
  const long long NWR = (long long)NREL * CH * CH / 4;
  const long long NWT = (long long)NTYP * CH * CH / 4;
  long long i4 = (long long)blockIdx.x * 256 + threadIdx.x;
  const float* src; ushort* dst; long long off;
  if (i4 < NXB) { src = xsrc; dst = xb; off = i4; }
  else if (i4 < NXB + NXT) { src = xt; dst = xtb; off = i4 - NXB; }
  else if (i4 < NXB + NXT + NWR) { src = relw; dst = wb; off = i4 - NXB - NXT; }
  else if (i4 < NXB + NXT + NWR + NWT) {
    src = rootw; dst = wb + (size_t)NREL * CH * CH; off = i4 - NXB - NXT - NWR;
  } else return;
  float4 v = *(const float4*)(src + off * 4);
  uint lo = (uint)f2b(v.x) | ((uint)f2b(v.y) << 16);
  uint hi = (uint)f2b(v.z) | ((uint)f2b(v.w) << 16);
  *(uint2*)(dst + off * 4) = make_uint2(lo, hi);
}

// ---- main kernel: 1 block = 32 dst rows, full 128-col output, write-once ----
// LDS agg layout de-interleaved: channel c stored at slot (c>>1) + 64*(c&1)
// -> both even and odd ds_atomic ops are 2-lanes/bank (free).
__global__ __launch_bounds__(128) void k_main(const ushort* __restrict__ xb,
    const ushort* __restrict__ xtb, const ushort* __restrict__ wb,
    const int* __restrict__ eoff, const uint2* __restrict__ sedge,
    const int* __restrict__ ntyp, const float* __restrict__ rootb,
    float* __restrict__ out) {
  __shared__ float agg[TR * CH];          // 16 KB
  __shared__ ushort strip[2 * 16 * CH];   // 8 KB
  __shared__ float rb[NTYP * CH];         // 2 KB
  int wv = threadIdx.x >> 6, ln = threadIdx.x & 63;
  int m = ln & 15, quad = ln >> 4;
  int d0 = blockIdx.x * TR;
  ushort* mystrip = strip + wv * 16 * CH;

  ((f32x4*)rb)[threadIdx.x] = ((const f32x4*)rootb)[threadIdx.x];  // 512 floats

  f32x4 acc[8];
#pragma unroll
  for (int ct = 0; ct < 8; ++ct) acc[ct] = (f32x4){0.f, 0.f, 0.f, 0.f};

  for (int r = 0; r < NREL; ++r) {
    // zero agg tile
#pragma unroll
    for (int i = 0; i < TR * CH / (128 * 4); ++i)
      *(f32x4*)&agg[(i * 128 + threadIdx.x) * 4] = (f32x4){0.f, 0.f, 0.f, 0.f};
    __syncthreads();

    int p0 = r * NTGT + d0;
    int dhi = (d0 + TR < NTGT) ? d0 + TR : NTGT;
    int lo = eoff[p0], hi = eoff[r * NTGT + dhi];
    int n = hi - lo;
    int half = (n + 1) >> 1;
    int s0 = lo + wv * half;
    int e1 = lo + ((wv == 0) ? half : n);
    int i = s0;
    for (; i + 1 < e1; i += 2) {
      uint2 a = sedge[i], b = sedge[i + 1];
      uint ua = *(const uint*)(xb + (size_t)a.x * CH + (ln << 1));
      uint ub = *(const uint*)(xb + (size_t)b.x * CH + (ln << 1));
      int ra = (int)a.y - d0, rbw = (int)b.y - d0;
      atomicAdd(&agg[ra * CH + ln], bl(ua));
      atomicAdd(&agg[ra * CH + 64 + ln], bh(ua));
      atomicAdd(&agg[rbw * CH + ln], bl(ub));
      atomicAdd(&agg[rbw * CH + 64 + ln], bh(ub));
    }
    if (i < e1) {
      uint2 a = sedge[i];
      uint ua = *(const uint*)(xb + (size_t)a.x * CH + (ln << 1));
      int ra = (int)a.y - d0;
      atomicAdd(&agg[ra * CH + ln], bl(ua));
      atomicAdd(&agg[ra * CH + 64 + ln], bh(ua));
    }
    __syncthreads();

    // pack 16 rows (this wave's strip): scale by 1/n, bf16
    for (int ii = 0; ii < 16; ++ii) {
      int d = d0 + wv * 16 + ii;
      float inv = 0.f;
      if (d < NTGT) {
        int pp = r * NTGT + d;
        int c = eoff[pp + 1] - eoff[pp];
        inv = (c > 0) ? 1.0f / (float)c : 0.f;
      }
      int row = wv * 16 + ii;
      float ax = agg[row * CH + ln] * inv;
      float ay = agg[row * CH + 64 + ln] * inv;
      uint w = bfpack(ax, ay);
      int c = ln >> 2;
      *(uint*)&mystrip[((ii * 16 + (c ^ ii)) << 3) + ((ln & 3) << 1)] = w;
    }
    __syncthreads();  // agg consumed; safe to re-zero next rel

    bf16x8 aF[4];
#pragma unroll
    for (int ks = 0; ks < 4; ++ks)
      aF[ks] = *(const bf16x8*)&mystrip[(m * 16 + ((ks * 4 + quad) ^ m)) << 3];
    const ushort* W = wb + (size_t)r * CH * CH;
#pragma unroll
    for (int ct = 0; ct < 8; ++ct) {
      int nn = ct * 16 + m;
#pragma unroll
      for (int ks = 0; ks < 4; ++ks) {
        bf16x8 bF = *(const bf16x8*)(W + (size_t)nn * CH + ks * 32 + quad * 8);
        acc[ct] = __builtin_amdgcn_mfma_f32_16x16x32_bf16(aF[ks], bF, acc[ct], 0, 0, 0);
      }
    }
  }

  // root linear: 4 type-masked GEMM passes (wave-local strips, no barriers)
  for (int t = 0; t < NTYP; ++t) {
    for (int ii = 0; ii < 16; ++ii) {
      int d = d0 + wv * 16 + ii;
      uint w = 0;
      if (d < NTGT && ntyp[d] == t)
        w = *(const uint*)(xtb + (size_t)d * CH + (ln << 1));
      int c = ln >> 2;
      *(uint*)&mystrip[((ii * 16 + (c ^ ii)) << 3) + ((ln & 3) << 1)] = w;
    }
    bf16x8 aF[4];
#pragma unroll
    for (int ks = 0; ks < 4; ++ks)
      aF[ks] = *(const bf16x8*)&mystrip[(m * 16 + ((ks * 4 + quad) ^ m)) << 3];
    const ushort* W = wb + (size_t)(NREL + t) * CH * CH;
#pragma unroll
    for (int ct = 0; ct < 8; ++ct) {
      int nn = ct * 16 + m;
#pragma unroll
      for (int ks = 0; ks < 4; ++ks) {
        bf16x8 bF = *(const bf16x8*)(W + (size_t)nn * CH + ks * 32 + quad * 8);
        acc[ct] = __builtin_amdgcn_mfma_f32_16x16x32_bf16(aF[ks], bF, acc[ct], 0, 0, 0);
      }
    }
  }

  // epilogue: bias + single plain store per element
#pragma unroll
  for (int reg = 0; reg < 4; ++reg) {
    int d = d0 + wv * 16 + quad * 4 + reg;
    if (d < NTGT) {
      int t = ntyp[d];
#pragma unroll
      for (int ct = 0; ct < 8; ++ct) {
        int col = ct * 16 + m;
        out[(size_t)d * CH + col] = acc[ct][reg] + rb[t * CH + col];
      }
    }
  }
}

extern "C" void kernel_launch(void* const* d_in, const int* in_sizes, int n_in,
                              void* d_out, int out_size, void* d_ws, size_t ws_size,
                              hipStream_t stream) {
  (void)in_sizes; (void)n_in; (void)out_size; (void)ws_size;
  const float* xsrc  = (const float*)d_in[0];
  const float* xt    = (const float*)d_in[1];
  const float* relw  = (const float*)d_in[2];
  const float* rootw = (const float*)d_in[3];
  const float* rootb = (const float*)d_in[4];
  const int* esrc = (const int*)d_in[5];
  const int* edst = (const int*)d_in[6];
  const int* etyp = (const int*)d_in[7];
  const int* ntyp = (const int*)d_in[8];
  float* out = (float*)d_out;

  char* ws = (char*)d_ws;
  int*   cnt   = (int*)(ws + CNT_O);
  int*   eoff  = (int*)(ws + EOFF_O);
  int*   cur   = (int*)(ws + CUR_O);
  int*   bsE   = (int*)(ws + BSE_O);
  int*   bbE   = (int*)(ws + BBE_O);
  uint2* sedge = (uint2*)(ws + SEDGE_O);
  ushort* wb   = (ushort*)(ws + WB_O);
  ushort* xb   = (ushort*)(ws + XB_O);
  ushort* xtb  = (ushort*)(ws + XTB_O);

  hipMemsetAsync(ws, 0, ZERO_END, stream);
  k_count<<<dim3((NE + 255) / 256), dim3(256), 0, stream>>>(edst, etyp, cnt);
  k_s1<<<dim3(NB), dim3(256), 0, stream>>>(cnt, bsE);
  k_s2<<<dim3(1), dim3(512), 0, stream>>>(bsE, bbE, eoff);
  k_s3<<<dim3(NB), dim3(256), 0, stream>>>(cnt, bbE, eoff, cur);
  k_esort<<<dim3((NE + 255) / 256), dim3(256), 0, stream>>>(esrc, edst, etyp, cur, sedge);
  {
    long long tot4 = (long long)NSRC * CH / 4 + (long long)NTGT * CH / 4 +
                     (long long)(NREL + NTYP) * CH * CH / 4;
    k_conv<<<dim3((unsigned)((tot4 + 255) / 256)), dim3(256), 0, stream>>>(
        xsrc, xt, relw, rootw, xb, xtb, wb);
  }
  k_main<<<dim3(NTILE), dim3(128), 0, stream>>>(xb, xtb, wb, eoff, sedge, ntyp, rootb, out);
}

// Round 6
// 663.673 us; speedup vs baseline: 1.2993x; 1.2993x over previous
//
#include <hip/hip_runtime.h>

#define NSRC 100000
#define NTGT 50000
#define NE   600000
#define CH   128
#define NREL 7
#define NTYP 4
#define NP   (NREL * NTGT)           // 350000 (rel,dst) pairs
#define NB   ((NP + 1023) / 1024)    // 342 scan blocks
#define NTILE ((NTGT + 63) / 64)     // 782

typedef __attribute__((ext_vector_type(4))) float f32x4;
typedef __attribute__((ext_vector_type(8))) short bf16x8;
typedef unsigned int uint;
typedef unsigned short ushort;

// ---- workspace layout ----
static constexpr size_t A256(size_t x) { return (x + 255) & ~(size_t)255; }
static constexpr size_t CNT_O   = 0;                                  // int[NP] (zeroed)
static constexpr size_t ZERO_END= A256(CNT_O + (size_t)NP * 4);
static constexpr size_t BSE_O   = ZERO_END;                           // int[NB]
static constexpr size_t BSR_O   = A256(BSE_O + (size_t)NB * 4);
static constexpr size_t BBE_O   = A256(BSR_O + (size_t)NB * 4);
static constexpr size_t BBR_O   = A256(BBE_O + (size_t)NB * 4);
static constexpr size_t CUR_O   = A256(BBR_O + (size_t)NB * 4);       // int[NP]
static constexpr size_t PLO_O   = A256(CUR_O + (size_t)NP * 4);       // int[NP]
static constexpr size_t PINV_O  = A256(PLO_O + (size_t)NP * 4);       // float[NP]
static constexpr size_t PDST_O  = A256(PINV_O + (size_t)NP * 4);      // int[NP]
static constexpr size_t RID_O   = A256(PDST_O + (size_t)NP * 4);      // int[NP]
static constexpr size_t RELO_O  = A256(RID_O + (size_t)NP * 4);       // int[NREL+1]
static constexpr size_t SEDGE_O = A256(RELO_O + 64);                  // uint2[NE] 4.8MB
static constexpr size_t WB_O    = A256(SEDGE_O + (size_t)NE * 8);     // bf16[11*CH*CH]
static constexpr size_t XB_O    = A256(WB_O + (size_t)(NREL + NTYP) * CH * CH * 2);
static constexpr size_t XTB_O   = A256(XB_O + (size_t)NSRC * CH * 2);

__device__ __forceinline__ uint bfpack(float a, float b) {
  uint ua = __float_as_uint(a); ua = (ua + 0x7fff + ((ua >> 16) & 1)) >> 16;
  uint ub = __float_as_uint(b); ub = (ub + 0x7fff + ((ub >> 16) & 1)) >> 16;
  return ua | (ub << 16);
}
__device__ __forceinline__ ushort f2b(float x) {
  uint u = __float_as_uint(x);
  return (ushort)((u + 0x7fff + ((u >> 16) & 1)) >> 16);
}
__device__ __forceinline__ float bl(uint u) { return __uint_as_float(u << 16); }
__device__ __forceinline__ float bh(uint u) { return __uint_as_float(u & 0xffff0000u); }

__global__ void k_count(const int* __restrict__ edst, const int* __restrict__ etyp,
                        int* __restrict__ cnt) {
  int i = blockIdx.x * 256 + threadIdx.x;
  if (i < NE) atomicAdd(&cnt[etyp[i] * NTGT + edst[i]], 1);
}

// stage 1: per-1024-pair block sums of (edges, nonzero pairs)
__global__ __launch_bounds__(256) void k_s1(const int* __restrict__ cnt,
                                            int* __restrict__ bsE, int* __restrict__ bsR) {
  __shared__ int sE[256], sR[256];
  int t = threadIdx.x, p0 = blockIdx.x * 1024 + t * 4;
  int e = 0, r = 0;
#pragma unroll
  for (int j = 0; j < 4; ++j) {
    int p = p0 + j;
    if (p < NP) { int c = cnt[p]; e += c; r += (c > 0); }
  }
  sE[t] = e; sR[t] = r; __syncthreads();
  for (int s = 128; s > 0; s >>= 1) {
    if (t < s) { sE[t] += sE[t + s]; sR[t] += sR[t + s]; }
    __syncthreads();
  }
  if (t == 0) { bsE[blockIdx.x] = sE[0]; bsR[blockIdx.x] = sR[0]; }
}

// stage 2: exclusive scan of block sums; total rows -> reloff[NREL]
__global__ __launch_bounds__(512) void k_s2(const int* __restrict__ bsE, const int* __restrict__ bsR,
                                            int* __restrict__ bbE, int* __restrict__ bbR,
                                            int* __restrict__ reloff) {
  __shared__ int sE[512], sR[512];
  int t = threadIdx.x;
  int e = (t < NB) ? bsE[t] : 0;
  int r = (t < NB) ? bsR[t] : 0;
  sE[t] = e; sR[t] = r; __syncthreads();
  for (int s = 1; s < 512; s <<= 1) {
    int ae = 0, ar = 0;
    if (t >= s) { ae = sE[t - s]; ar = sR[t - s]; }
    __syncthreads();
    sE[t] += ae; sR[t] += ar;
    __syncthreads();
  }
  if (t < NB) { bbE[t] = sE[t] - e; bbR[t] = sR[t] - r; }
  if (t == NB - 1) reloff[NREL] = sR[t];
}

// stage 3: per-pair offsets -> cur; compact arrays plo/pinv/pdst/rowid; reloff
__global__ __launch_bounds__(256) void k_s3(const int* __restrict__ cnt,
    const int* __restrict__ bbE, const int* __restrict__ bbR,
    int* __restrict__ cur, int* __restrict__ plo, float* __restrict__ pinv,
    int* __restrict__ pdst, int* __restrict__ rowid, int* __restrict__ reloff) {
  __shared__ int sE[256], sR[256];
  int t = threadIdx.x, p0 = blockIdx.x * 1024 + t * 4;
  int c[4]; int e = 0, r = 0;
#pragma unroll
  for (int j = 0; j < 4; ++j) {
    int p = p0 + j;
    c[j] = (p < NP) ? cnt[p] : 0;
    e += c[j]; r += (c[j] > 0);
  }
  sE[t] = e; sR[t] = r; __syncthreads();
  for (int s = 1; s < 256; s <<= 1) {
    int ae = 0, ar = 0;
    if (t >= s) { ae = sE[t - s]; ar = sR[t - s]; }
    __syncthreads();
    sE[t] += ae; sR[t] += ar;
    __syncthreads();
  }
  int baseE = bbE[blockIdx.x] + sE[t] - e;
  int baseR = bbR[blockIdx.x] + sR[t] - r;
#pragma unroll
  for (int j = 0; j < 4; ++j) {
    int p = p0 + j;
    if (p < NP) {
      cur[p] = baseE;
      if ((p % NTGT) == 0) reloff[p / NTGT] = baseR;
      if (c[j] > 0) {
        plo[baseR] = baseE;
        pinv[baseR] = 1.0f / (float)c[j];
        pdst[baseR] = p % NTGT;
        rowid[p] = baseR;
        baseR++;
      }
      baseE += c[j];
    }
  }
}

// sort edges by (rel,dst); store (src, compact-row-id)
__global__ void k_esort(const int* __restrict__ esrc, const int* __restrict__ edst,
                        const int* __restrict__ etyp, const int* __restrict__ rowid,
                        int* __restrict__ cur, uint2* __restrict__ sedge) {
  int i = blockIdx.x * 256 + threadIdx.x;
  if (i < NE) {
    int p = etyp[i] * NTGT + edst[i];
    int pos = atomicAdd(&cur[p], 1);
    sedge[pos] = make_uint2((uint)esrc[i], (uint)rowid[p]);
  }
}

// fused: fp32->bf16 conversion (x_src, x_target, weights) + bias prefill of out
__global__ void k_prep(const float* __restrict__ xsrc, const float* __restrict__ xt,
                       const float* __restrict__ relw, const float* __restrict__ rootw,
                       const float* __restrict__ rootb, const int* __restrict__ ntyp,
                       ushort* __restrict__ xb, ushort* __restrict__ xtb,
                       ushort* __restrict__ wb, float* __restrict__ out) {
  const long long NXB = (long long)NSRC * CH / 4;
  const long long NXT = (long long)NTGT * CH / 4;
  const long long NWR = (long long)NREL * CH * CH / 4;
  const long long NWT = (long long)NTYP * CH * CH / 4;
  const long long NBI = (long long)NTGT * CH / 4;
  long long i4 = (long long)blockIdx.x * 256 + threadIdx.x;
  const float* src; ushort* dst; long long off;
  if (i4 < NXB) { src = xsrc; dst = xb; off = i4; }
  else if (i4 < NXB + NXT) { src = xt; dst = xtb; off = i4 - NXB; }
  else if (i4 < NXB + NXT + NWR) { src = relw; dst = wb; off = i4 - NXB - NXT; }
  else if (i4 < NXB + NXT + NWR + NWT) {
    src = rootw; dst = wb + (size_t)NREL * CH * CH; off = i4 - NXB - NXT - NWR;
  } else if (i4 < NXB + NXT + NWR + NWT + NBI) {
    long long o = (i4 - NXB - NXT - NWR - NWT) * 4;
    int d = (int)(o >> 7), c = (int)(o & 127);
    int t = ntyp[d];
    *(float4*)(out + (size_t)d * CH + c) = *(const float4*)(rootb + (size_t)t * CH + c);
    return;
  } else return;
  float4 v = *(const float4*)(src + off * 4);
  uint lo = (uint)f2b(v.x) | ((uint)f2b(v.y) << 16);
  uint hi = (uint)f2b(v.z) | ((uint)f2b(v.w) << 16);
  *(uint2*)(dst + off * 4) = make_uint2(lo, hi);
}

// ---- main fused kernel: grid (NREL+1, NTILE), 256 thr ----
// u<NREL: edge-parallel LDS agg of 64 compact rows + MFMA + atomic epilogue.
// u==NREL: root linear, type-masked 4-pass MFMA over dsts [64y, 64y+64).
// LDS agg layout: channel c of row -> row*128 + (c&1)*64 + (((c>>3) ^ (row&15))<<2) + ((c>>1)&3)
// (de-interleaved halves + row-XOR chunk swizzle => conflict-free ds_add and ds_read_b128)
__global__ __launch_bounds__(256) void k_fuse(const ushort* __restrict__ xb,
    const ushort* __restrict__ xtb, const ushort* __restrict__ wb,
    const int* __restrict__ plo, const float* __restrict__ pinv,
    const int* __restrict__ pdst, const int* __restrict__ reloff,
    const uint2* __restrict__ sedge, const int* __restrict__ ntyp,
    float* __restrict__ out) {
  __shared__ float agg[64 * CH];  // 32 KB
  int u = blockIdx.x, ty = blockIdx.y;
  int wv = threadIdx.x >> 6, ln = threadIdx.x & 63;
  int m = ln & 15, quad = ln >> 4;
  f32x4 acc[8];
#pragma unroll
  for (int ct = 0; ct < 8; ++ct) acc[ct] = (f32x4){0.f, 0.f, 0.f, 0.f};

  if (u < NREL) {
    int base = reloff[u], relend = reloff[u + 1];
    int gr0 = base + ty * 64;
    if (gr0 >= relend) return;
    int total = reloff[NREL];
    int grL = (gr0 + 63 < relend - 1) ? gr0 + 63 : relend - 1;

#pragma unroll
    for (int i = 0; i < 8; ++i)
      ((f32x4*)agg)[i * 256 + threadIdx.x] = (f32x4){0.f, 0.f, 0.f, 0.f};
    __syncthreads();

    int elo = plo[gr0];
    int ehi = (grL + 1 < total) ? plo[grL + 1] : NE;
    // per-lane LDS addr components for channels 2*ln and 2*ln+1
    int cj = ln >> 2, wi = ln & 3;
    int i = elo + wv;
    for (; i + 4 < ehi; i += 8) {
      uint2 e0 = sedge[i], e1 = sedge[i + 4];
      uint x0 = *(const uint*)(xb + (size_t)e0.x * CH + (ln << 1));
      uint x1 = *(const uint*)(xb + (size_t)e1.x * CH + (ln << 1));
      int r0 = (int)e0.y - gr0, r1 = (int)e1.y - gr0;
      int a0 = r0 * CH + ((cj ^ (r0 & 15)) << 2) + wi;
      int a1 = r1 * CH + ((cj ^ (r1 & 15)) << 2) + wi;
      atomicAdd(&agg[a0], bl(x0));
      atomicAdd(&agg[a0 + 64], bh(x0));
      atomicAdd(&agg[a1], bl(x1));
      atomicAdd(&agg[a1 + 64], bh(x1));
    }
    if (i < ehi) {
      uint2 e0 = sedge[i];
      uint x0 = *(const uint*)(xb + (size_t)e0.x * CH + (ln << 1));
      int r0 = (int)e0.y - gr0;
      int a0 = r0 * CH + ((cj ^ (r0 & 15)) << 2) + wi;
      atomicAdd(&agg[a0], bl(x0));
      atomicAdd(&agg[a0 + 64], bh(x0));
    }
    __syncthreads();

    // A-frags from LDS (wave-local rows wv*16+m), apply 1/n, pack bf16
    int row = wv * 16 + m;
    int gr = gr0 + row;
    float inv = (gr < relend) ? pinv[gr] : 0.f;
    bf16x8 aF[4];
#pragma unroll
    for (int ks = 0; ks < 4; ++ks) {
      int t = ks * 4 + quad;
      f32x4 ev = *(const f32x4*)&agg[row * CH + ((t ^ m) << 2)];
      f32x4 od = *(const f32x4*)&agg[row * CH + 64 + ((t ^ m) << 2)];
      uint4 pk;
      pk.x = bfpack(ev.x * inv, od.x * inv);
      pk.y = bfpack(ev.y * inv, od.y * inv);
      pk.z = bfpack(ev.z * inv, od.z * inv);
      pk.w = bfpack(ev.w * inv, od.w * inv);
      aF[ks] = *(bf16x8*)&pk;
    }
    const ushort* W = wb + (size_t)u * CH * CH;
#pragma unroll
    for (int ct = 0; ct < 8; ++ct) {
      int nn = ct * 16 + m;
#pragma unroll
      for (int ks = 0; ks < 4; ++ks) {
        bf16x8 bF = *(const bf16x8*)(W + (size_t)nn * CH + ks * 32 + quad * 8);
        acc[ct] = __builtin_amdgcn_mfma_f32_16x16x32_bf16(aF[ks], bF, acc[ct], 0, 0, 0);
      }
    }
    int dmap[4];
#pragma unroll
    for (int reg = 0; reg < 4; ++reg) {
      int gre = gr0 + wv * 16 + quad * 4 + reg;
      dmap[reg] = (gre < relend) ? pdst[gre] : -1;
    }
#pragma unroll
    for (int ct = 0; ct < 8; ++ct)
#pragma unroll
      for (int reg = 0; reg < 4; ++reg)
        if (dmap[reg] >= 0)
          unsafeAtomicAdd(&out[(size_t)dmap[reg] * CH + ct * 16 + m], acc[ct][reg]);
  } else {
    // root: dsts [64*ty, 64*ty+64), type-masked 4-pass
    int d0 = ty * 64;
    int drow = d0 + wv * 16 + m;
    bool okr = drow < NTGT;
    int tmy = okr ? ntyp[drow] : -1;
    bf16x8 zf;
    *(uint4*)&zf = make_uint4(0, 0, 0, 0);
    bf16x8 aF[4];
#pragma unroll
    for (int ks = 0; ks < 4; ++ks)
      aF[ks] = okr ? *(const bf16x8*)(xtb + (size_t)drow * CH + (ks * 4 + quad) * 8) : zf;
#pragma unroll
    for (int t = 0; t < NTYP; ++t) {
      bf16x8 aT[4];
#pragma unroll
      for (int ks = 0; ks < 4; ++ks) aT[ks] = (tmy == t) ? aF[ks] : zf;
      const ushort* W = wb + (size_t)(NREL + t) * CH * CH;
#pragma unroll
      for (int ct = 0; ct < 8; ++ct) {
        int nn = ct * 16 + m;
#pragma unroll
        for (int ks = 0; ks < 4; ++ks) {
          bf16x8 bF = *(const bf16x8*)(W + (size_t)nn * CH + ks * 32 + quad * 8);
          acc[ct] = __builtin_amdgcn_mfma_f32_16x16x32_bf16(aT[ks], bF, acc[ct], 0, 0, 0);
        }
      }
    }
#pragma unroll
    for (int reg = 0; reg < 4; ++reg) {
      int d = d0 + wv * 16 + quad * 4 + reg;
      if (d < NTGT)
#pragma unroll
        for (int ct = 0; ct < 8; ++ct)
          unsafeAtomicAdd(&out[(size_t)d * CH + ct * 16 + m], acc[ct][reg]);
    }
  }
}

extern "C" void kernel_launch(void* const* d_in, const int* in_sizes, int n_in,
                              void* d_out, int out_size, void* d_ws, size_t ws_size,
                              hipStream_t stream) {
  (void)in_sizes; (void)n_in; (void)out_size; (void)ws_size;
  const float* xsrc  = (const float*)d_in[0];
  const float* xt    = (const float*)d_in[1];
  const float* relw  = (const float*)d_in[2];
  const float* rootw = (const float*)d_in[3];
  const float* rootb = (const float*)d_in[4];
  const int* esrc = (const int*)d_in[5];
  const int* edst = (const int*)d_in[6];
  const int* etyp = (const int*)d_in[7];
  const int* ntyp = (const int*)d_in[8];
  float* out = (float*)d_out;

  char* ws = (char*)d_ws;
  int*   cnt    = (int*)(ws + CNT_O);
  int*   bsE    = (int*)(ws + BSE_O);
  int*   bsR    = (int*)(ws + BSR_O);
  int*   bbE    = (int*)(ws + BBE_O);
  int*   bbR    = (int*)(ws + BBR_O);
  int*   cur    = (int*)(ws + CUR_O);
  int*   plo    = (int*)(ws + PLO_O);
  float* pinv   = (float*)(ws + PINV_O);
  int*   pdst   = (int*)(ws + PDST_O);
  int*   rowid  = (int*)(ws + RID_O);
  int*   reloff = (int*)(ws + RELO_O);
  uint2* sedge  = (uint2*)(ws + SEDGE_O);
  ushort* wb    = (ushort*)(ws + WB_O);
  ushort* xb    = (ushort*)(ws + XB_O);
  ushort* xtb   = (ushort*)(ws + XTB_O);

  hipMemsetAsync(ws, 0, ZERO_END, stream);
  k_count<<<dim3((NE + 255) / 256), dim3(256), 0, stream>>>(edst, etyp, cnt);
  k_s1<<<dim3(NB), dim3(256), 0, stream>>>(cnt, bsE, bsR);
  k_s2<<<dim3(1), dim3(512), 0, stream>>>(bsE, bsR, bbE, bbR, reloff);
  k_s3<<<dim3(NB), dim3(256), 0, stream>>>(cnt, bbE, bbR, cur, plo, pinv, pdst, rowid, reloff);
  k_esort<<<dim3((NE + 255) / 256), dim3(256), 0, stream>>>(esrc, edst, etyp, rowid, cur, sedge);
  {
    long long tot4 = (long long)NSRC * CH / 4 + (long long)NTGT * CH / 4 +
                     (long long)(NREL + NTYP) * CH * CH / 4 + (long long)NTGT * CH / 4;
    k_prep<<<dim3((unsigned)((tot4 + 255) / 256)), dim3(256), 0, stream>>>(
        xsrc, xt, relw, rootw, rootb, ntyp, xb, xtb, wb, out);
  }
  k_fuse<<<dim3(NREL + 1, NTILE), dim3(256), 0, stream>>>(
      xb, xtb, wb, plo, pinv, pdst, reloff, sedge, ntyp, out);
}